// Round 1
// baseline (441.735 us; speedup 1.0000x reference)
//
#include <hip/hip_runtime.h>

#define ALPHA 0.2f

// consts layout in ws (after the two sum arrays):
//   [0..63]  w_n   = W_node @ a_node[64:128]
//   [64..79] w_e   = W_edge @ a_edge[64:128]
//   [80]     c_node = (graph_fts@W_graph) . a_node[0:64]
//   [81]     c_edge = (graph_fts@W_graph) . a_edge[0:64]
__global__ void ga_consts_kernel(const float* __restrict__ graph_fts,
                                 const float* __restrict__ W_node,
                                 const float* __restrict__ W_edge,
                                 const float* __restrict__ W_graph,
                                 const float* __restrict__ a_node,
                                 const float* __restrict__ a_edge,
                                 float* __restrict__ consts) {
    const int k = threadIdx.x;  // 0..63, one wave

    // g_v[k] = sum_c graph_fts[c] * W_graph[c,k]
    float g = 0.f;
    #pragma unroll
    for (int c = 0; c < 32; ++c) g += graph_fts[c] * W_graph[c * 64 + k];

    // w_n[k] = sum_c W_node[k,c] * a_node[64+c]
    float wn = 0.f;
    #pragma unroll
    for (int c = 0; c < 64; ++c) wn += W_node[k * 64 + c] * a_node[64 + c];
    consts[k] = wn;

    if (k < 16) {
        float we = 0.f;
        #pragma unroll
        for (int c = 0; c < 64; ++c) we += W_edge[k * 64 + c] * a_edge[64 + c];
        consts[64 + k] = we;
    }

    // c_node/c_edge: full-wave (64-lane) reduction of g_v[k]*a[k]
    float cn = g * a_node[k];
    float ce = g * a_edge[k];
    #pragma unroll
    for (int off = 32; off > 0; off >>= 1) {
        cn += __shfl_down(cn, off);
        ce += __shfl_down(ce, off);
    }
    if (k == 0) { consts[80] = cn; consts[81] = ce; }
}

// 16 lanes cooperate per node row (64 f32 = 4 f32/lane). Fully coalesced:
// one wave's float4 loads cover 4 consecutive rows = 1 KiB contiguous.
__global__ void ga_node_att_kernel(const float* __restrict__ node_fts,
                                   const int* __restrict__ seg_ids,
                                   const float* __restrict__ consts,
                                   float* __restrict__ out_e,      // d_out[0:N)
                                   float* __restrict__ sums_node,  // ws, zeroed
                                   int N) {
    const int lane16 = threadIdx.x & 15;
    const int gid = blockIdx.x * blockDim.x + threadIdx.x;
    const int group = gid >> 4;
    const int ngroups = (gridDim.x * blockDim.x) >> 4;

    const float4 w = *reinterpret_cast<const float4*>(&consts[lane16 * 4]);
    const float c_node = consts[80];

    for (int row = group; row < N; row += ngroups) {
        const float4 x = *reinterpret_cast<const float4*>(
            &node_fts[(size_t)row * 64 + lane16 * 4]);
        float d = x.x * w.x + x.y * w.y + x.z * w.z + x.w * w.w;
        d += __shfl_xor(d, 1);
        d += __shfl_xor(d, 2);
        d += __shfl_xor(d, 4);
        d += __shfl_xor(d, 8);
        if (lane16 == 0) {
            float att = c_node + d;
            att = att > 0.f ? att : ALPHA * att;          // leaky_relu
            att = fminf(fmaxf(att, -2.f), 2.f);           // clip
            const float e = expf(att);
            out_e[row] = e;
            atomicAdd(&sums_node[seg_ids[row]], e);
        }
    }
}

// 4 lanes cooperate per edge row (16 f32 = 4 f32/lane).
__global__ void ga_edge_att_kernel(const float* __restrict__ edges,
                                   const int* __restrict__ seg_ids,
                                   const float* __restrict__ consts,
                                   float* __restrict__ out_e,      // d_out[N:2N)
                                   float* __restrict__ sums_edge,  // ws, zeroed
                                   int E) {
    const int lane4 = threadIdx.x & 3;
    const int gid = blockIdx.x * blockDim.x + threadIdx.x;
    const int group = gid >> 2;
    const int ngroups = (gridDim.x * blockDim.x) >> 2;

    const float4 w = *reinterpret_cast<const float4*>(&consts[64 + lane4 * 4]);
    const float c_edge = consts[81];

    for (int row = group; row < E; row += ngroups) {
        const float4 x = *reinterpret_cast<const float4*>(
            &edges[(size_t)row * 16 + lane4 * 4]);
        float d = x.x * w.x + x.y * w.y + x.z * w.z + x.w * w.w;
        d += __shfl_xor(d, 1);
        d += __shfl_xor(d, 2);
        if (lane4 == 0) {
            float att = c_edge + d;
            att = att > 0.f ? att : ALPHA * att;
            att = fminf(fmaxf(att, -2.f), 2.f);
            const float e = expf(att);
            out_e[row] = e;
            atomicAdd(&sums_edge[seg_ids[row]], e);
        }
    }
}

// In-place normalize both outputs; one seg_ids read serves both halves.
__global__ void ga_norm_kernel(const int* __restrict__ seg_ids,
                               const float* __restrict__ sums_node,
                               const float* __restrict__ sums_edge,
                               float* __restrict__ out, int N) {
    int j = blockIdx.x * blockDim.x + threadIdx.x;
    const int stride = gridDim.x * blockDim.x;
    for (; j < N; j += stride) {
        const int s = seg_ids[j];
        out[j]     = out[j]     / sums_node[s];
        out[N + j] = out[N + j] / sums_edge[s];
    }
}

extern "C" void kernel_launch(void* const* d_in, const int* in_sizes, int n_in,
                              void* d_out, int out_size, void* d_ws, size_t ws_size,
                              hipStream_t stream) {
    const float* node_fts  = (const float*)d_in[0];
    // d_in[1] (edge_fts) is unused by the reference computation.
    const float* graph_fts = (const float*)d_in[2];
    const float* edges     = (const float*)d_in[3];
    const int*   seg_ids   = (const int*)  d_in[4];
    const float* W_node    = (const float*)d_in[5];
    const float* W_edge    = (const float*)d_in[6];
    const float* W_graph   = (const float*)d_in[7];
    const float* a_node    = (const float*)d_in[8];
    const float* a_edge    = (const float*)d_in[9];

    const int N = in_sizes[0] / 64;   // node rows
    const int E = in_sizes[4];        // edges == seg_ids count

    float* out       = (float*)d_out;
    float* sums_node = (float*)d_ws;            // [N]
    float* sums_edge = sums_node + N;           // [E] (segments counted over N)
    float* consts    = sums_edge + N;           // [96]

    // zero the segment-sum accumulators (ws is poisoned 0xAA before each call)
    hipMemsetAsync(d_ws, 0, (size_t)(2 * N) * sizeof(float), stream);

    ga_consts_kernel<<<1, 64, 0, stream>>>(graph_fts, W_node, W_edge, W_graph,
                                           a_node, a_edge, consts);
    ga_node_att_kernel<<<2048, 256, 0, stream>>>(node_fts, seg_ids, consts,
                                                 out, sums_node, N);
    ga_edge_att_kernel<<<1024, 256, 0, stream>>>(edges, seg_ids, consts,
                                                 out + N, sums_edge, E);
    ga_norm_kernel<<<2048, 256, 0, stream>>>(seg_ids, sums_node, sums_edge, out, N);
}